// Round 1
// baseline (1109.582 us; speedup 1.0000x reference)
//
#include <hip/hip_runtime.h>
#include <stdint.h>

#define COLS 65536
#define TPB 1024
#define CAP 4096
#define KSEL 32
#define NWAVES (TPB / 64)

__device__ __forceinline__ uint32_t flip32(float f) {
    uint32_t u = __float_as_uint(f);
    return u ^ ((u & 0x80000000u) ? 0xFFFFFFFFu : 0x80000000u);
}
__device__ __forceinline__ float unflip32(uint32_t k) {
    uint32_t u = k ^ ((k & 0x80000000u) ? 0x80000000u : 0xFFFFFFFFu);
    return __uint_as_float(u);
}
__device__ __forceinline__ unsigned long long shfl_xor_u64(unsigned long long v, int m) {
    int lo = __shfl_xor((int)(uint32_t)v, m, 64);
    int hi = __shfl_xor((int)(uint32_t)(v >> 32), m, 64);
    return ((unsigned long long)(uint32_t)hi << 32) | (unsigned long long)(uint32_t)lo;
}

__global__ __launch_bounds__(TPB)
void topk_scatter_kernel(const float* __restrict__ x, float* __restrict__ out) {
    __shared__ unsigned long long cand[CAP];          // 32 KiB
    __shared__ int s_cnt;
    __shared__ int s_wsum[NWAVES];
    __shared__ unsigned long long s_wmin[NWAVES];
    __shared__ int s_total;
    __shared__ unsigned long long s_kth;

    const int tid  = threadIdx.x;
    const int lane = tid & 63;
    const int wid  = tid >> 6;
    const int row  = blockIdx.x;
    const float4* __restrict__ xv = (const float4*)(x + (size_t)row * COLS);
    float4* __restrict__ ov = (float4*)(out + (size_t)row * COLS);

    // ---- Phase 1: collect candidate keys (flipped fp32 >= pivot), zero-fill output row.
    // Static pivot 2.75 works w.h.p. for N(0,1); bisection retry keeps it correct for any data.
    uint32_t pivHi = flip32(2.75f);
    uint32_t loH = 0u, hiH = 0xFFFFFFFFu;
    bool firstPass = true;
    int c = 0;

    for (int attempt = 0; attempt < 64; ++attempt) {
        if (tid == 0) s_cnt = 0;
        __syncthreads();
        #pragma unroll
        for (int j = 0; j < COLS / 4 / TPB; ++j) {      // 16 float4 per thread, coalesced
            const int vi = j * TPB + tid;
            const float4 v = xv[vi];
            if (firstPass) ov[vi] = make_float4(0.f, 0.f, 0.f, 0.f);
            const uint32_t bidx = (uint32_t)vi * 4u;
            const float vv[4] = {v.x, v.y, v.z, v.w};
            #pragma unroll
            for (int e = 0; e < 4; ++e) {
                const uint32_t k = flip32(vv[e]);
                if (k >= pivHi) {                        // rare (~195/row)
                    const int pos = atomicAdd(&s_cnt, 1);
                    if (pos < CAP) {
                        // key: (value desc, index asc) -> larger key = earlier in top_k order
                        cand[pos] = ((unsigned long long)k << 32)
                                  | (unsigned long long)(0xFFFFu - (bidx + e));
                    }
                }
            }
        }
        firstPass = false;
        __syncthreads();
        c = s_cnt;
        __syncthreads();                                 // all read c before next reset
        if (c >= KSEL && c <= CAP) break;
        if (c > CAP) { loH = pivHi; pivHi = pivHi + ((hiH - pivHi) >> 1); }
        else         { hiH = pivHi; pivHi = loH + ((pivHi - loH) >> 1); }
    }

    // ---- Phase 2: cache candidates in registers (<= 4 per thread).
    unsigned long long k0 = 0ull, k1 = 0ull, k2 = 0ull, k3 = 0ull;
    if (tid           < c) k0 = cand[tid];
    if (tid + TPB     < c) k1 = cand[tid + TPB];
    if (tid + 2 * TPB < c) k2 = cand[tid + 2 * TPB];
    if (tid + 3 * TPB < c) k3 = cand[tid + 3 * TPB];

    // ---- Phase 3: binary search for mid with count(key > mid) == 32.
    // Keys are distinct, so a cnt==32 window of width>=1 always lies inside (lo,hi): guaranteed hit.
    const unsigned long long pivot64 = ((unsigned long long)pivHi << 32) - 1ull;
    unsigned long long lo = pivot64, hi = ~0ull, mid = pivot64;
    const bool trivially = (c == KSEL);                  // mid = pivot64 already has cnt == 32
    for (int it = 0; it < 80 && !trivially; ++it) {
        mid = lo + ((hi - lo) >> 1);
        int local = (int)(k0 > mid) + (int)(k1 > mid) + (int)(k2 > mid) + (int)(k3 > mid);
        #pragma unroll
        for (int off = 32; off >= 1; off >>= 1) local += __shfl_xor(local, off, 64);
        if (lane == 0) s_wsum[wid] = local;
        __syncthreads();
        if (tid == 0) {
            int t = 0;
            #pragma unroll
            for (int w = 0; w < NWAVES; ++w) t += s_wsum[w];
            s_total = t;
        }
        __syncthreads();
        const int m = s_total;
        if (m == KSEL) break;
        if (m > KSEL) lo = mid; else hi = mid;
    }

    // ---- Phase 4: kth key = min{ key > mid }  (the rank-32 key).
    unsigned long long lmin = ~0ull;
    if (k0 > mid && k0 < lmin) lmin = k0;
    if (k1 > mid && k1 < lmin) lmin = k1;
    if (k2 > mid && k2 < lmin) lmin = k2;
    if (k3 > mid && k3 < lmin) lmin = k3;
    #pragma unroll
    for (int off = 32; off >= 1; off >>= 1) {
        const unsigned long long o = shfl_xor_u64(lmin, off);
        if (o < lmin) lmin = o;
    }
    if (lane == 0) s_wmin[wid] = lmin;
    __syncthreads();
    if (tid == 0) {
        unsigned long long t = ~0ull;
        #pragma unroll
        for (int w = 0; w < NWAVES; ++w) t = (s_wmin[w] < t) ? s_wmin[w] : t;
        s_kth = t;
    }
    __syncthreads();
    const unsigned long long kth = s_kth;

    // ---- Phase 5: scatter the 32 winners (idx/value decoded from the key; no row re-read).
    // Zero-fill stores were drained by the __syncthreads (vmcnt(0) before s_barrier).
    const unsigned long long ks[4] = {k0, k1, k2, k3};
    #pragma unroll
    for (int q = 0; q < 4; ++q) {
        const unsigned long long key = ks[q];
        if (key >= kth) {
            const uint32_t k32 = (uint32_t)(key >> 32);
            const uint32_t idx = 0xFFFFu - (uint32_t)(key & 0xFFFFull);
            out[(size_t)row * COLS + idx] = fmaxf(unflip32(k32), 0.f);
        }
    }
}

extern "C" void kernel_launch(void* const* d_in, const int* in_sizes, int n_in,
                              void* d_out, int out_size, void* d_ws, size_t ws_size,
                              hipStream_t stream) {
    const float* x = (const float*)d_in[0];
    float* out = (float*)d_out;
    const int rows = in_sizes[0] / COLS;
    hipLaunchKernelGGL(topk_scatter_kernel, dim3(rows), dim3(TPB), 0, stream, x, out);
}

// Round 2
// 704.600 us; speedup vs baseline: 1.5748x; 1.5748x over previous
//
#include <hip/hip_runtime.h>
#include <stdint.h>

#define COLS 65536
#define KSEL 32
#define PIV_HI 0xC0300000u   /* flip32(2.75f): rank-32/65536 threshold for N(0,1) is ~3.30 */

typedef __attribute__((ext_vector_type(4))) float f32x4;

__device__ __forceinline__ uint32_t flip32(float f) {
    uint32_t u = __float_as_uint(f);
    return u ^ ((u & 0x80000000u) ? 0xFFFFFFFFu : 0x80000000u);
}
__device__ __forceinline__ float unflip32(uint32_t k) {
    uint32_t u = k ^ ((k & 0x80000000u) ? 0x80000000u : 0xFFFFFFFFu);
    return __uint_as_float(u);
}

// ---------------- Phase 1: zero-fill output (write-only stream, NT stores) ----------------
__global__ __launch_bounds__(256)
void fill_zero_kernel(float* __restrict__ out, long long n4) {
    const long long stride = (long long)gridDim.x * blockDim.x;
    f32x4* o = (f32x4*)out;
    const f32x4 z = (f32x4)(0.f);
    for (long long g = (long long)blockIdx.x * blockDim.x + threadIdx.x; g < n4; g += stride)
        __builtin_nontemporal_store(z, &o[g]);
}

// ---------------- Phase 2: streaming candidate filter (read-only stream) ----------------
__global__ __launch_bounds__(256)
void collect_kernel(const float* __restrict__ x, unsigned long long* __restrict__ slots,
                    int* __restrict__ cnt, int cap2, long long n4) {
    const long long stride = (long long)gridDim.x * blockDim.x;
    const float4* xv = (const float4*)x;
    for (long long g = (long long)blockIdx.x * blockDim.x + threadIdx.x; g < n4; g += stride) {
        const float4 v = xv[g];
        const uint32_t f0 = flip32(v.x), f1 = flip32(v.y), f2 = flip32(v.z), f3 = flip32(v.w);
        const int n = (int)(f0 >= PIV_HI) + (int)(f1 >= PIV_HI)
                    + (int)(f2 >= PIV_HI) + (int)(f3 >= PIV_HI);
        if (n) {                                        // ~1.2% of lanes
            const int row = (int)(g >> 14);             // 16384 float4 per row
            const uint32_t col0 = ((uint32_t)g & 16383u) << 2;
            int pos = atomicAdd(&cnt[row], n);
            unsigned long long* base = slots + (size_t)row * (size_t)cap2;
            const uint32_t fs[4] = {f0, f1, f2, f3};
            #pragma unroll
            for (int e = 0; e < 4; ++e) {
                if (fs[e] >= PIV_HI) {
                    if (pos < cap2)
                        base[pos] = ((unsigned long long)fs[e] << 32)
                                  | (unsigned long long)(0xFFFFu - (col0 + e));
                    ++pos;
                }
            }
        }
    }
}

// ---------------- Phase 3: one wave per row — register bisection + scatter ----------------
__global__ __launch_bounds__(64)
void select_kernel(const float* __restrict__ x, const unsigned long long* __restrict__ slots,
                   const int* __restrict__ cnt, int cap2, float* __restrict__ out) {
    const int row = blockIdx.x;
    const int lane = threadIdx.x;
    const int c = cnt[row];

    if (c >= KSEL && c <= cap2) {
        // Load candidates into registers (<=16/lane; typically 4 rounds active).
        unsigned long long k[16];
        const unsigned long long* base = slots + (size_t)row * (size_t)cap2;
        #pragma unroll
        for (int i = 0; i < 16; ++i) {
            const int idx = i * 64 + lane;
            k[i] = (idx < c) ? base[idx] : 0ull;
        }
        // Bisect for mid with count(key > mid) == 32. Keys distinct (col bits) => guaranteed hit.
        unsigned long long lo = ((unsigned long long)PIV_HI << 32) - 1ull;  // count(>lo) == c
        unsigned long long hi = ~0ull;
        unsigned long long mid = lo;
        int m = c;
        for (int it = 0; it < 72 && m != KSEL; ++it) {
            mid = lo + ((hi - lo) >> 1);
            int local = 0;
            #pragma unroll
            for (int i = 0; i < 16; ++i) local += (int)(k[i] > mid);
            #pragma unroll
            for (int off = 32; off >= 1; off >>= 1) local += __shfl_xor(local, off, 64);
            m = local;
            if (m > KSEL) lo = mid; else if (m < KSEL) hi = mid;
        }
        // Scatter: keys > mid are exactly the top-32 in jax.lax.top_k order semantics.
        #pragma unroll
        for (int i = 0; i < 16; ++i) {
            if (k[i] > mid) {
                const uint32_t col = 0xFFFFu - (uint32_t)(k[i] & 0xFFFFull);
                out[(size_t)row * COLS + col] = fmaxf(unflip32((uint32_t)(k[i] >> 32)), 0.f);
            }
        }
    } else {
        // Correctness fallback (never taken for N(0,1)): full-row bisection from global.
        const float* xr = x + (size_t)row * COLS;
        unsigned long long lo = 0ull, hi = ~0ull, mid = 0ull;
        int m = -1;
        for (int it = 0; it < 80 && m != KSEL; ++it) {
            mid = lo + ((hi - lo) >> 1);
            int local = 0;
            for (int j = lane; j < COLS; j += 64) {
                const unsigned long long key =
                    ((unsigned long long)flip32(xr[j]) << 32)
                    | (unsigned long long)(0xFFFFu - (uint32_t)j);
                local += (int)(key > mid);
            }
            #pragma unroll
            for (int off = 32; off >= 1; off >>= 1) local += __shfl_xor(local, off, 64);
            m = local;
            if (m > KSEL) lo = mid; else if (m < KSEL) hi = mid;
        }
        for (int j = lane; j < COLS; j += 64) {
            const unsigned long long key =
                ((unsigned long long)flip32(xr[j]) << 32)
                | (unsigned long long)(0xFFFFu - (uint32_t)j);
            if (key > mid) out[(size_t)row * COLS + j] = fmaxf(xr[j], 0.f);
        }
    }
}

// ---------------- Last-resort fused kernel (used only if ws_size is tiny) ----------------
#define CAPF 4096
#define TPBF 1024
#define NWAVESF (TPBF / 64)
__global__ __launch_bounds__(TPBF)
void topk_fused_kernel(const float* __restrict__ x, float* __restrict__ out) {
    __shared__ unsigned long long cand[CAPF];
    __shared__ int s_cnt;
    __shared__ int s_wsum[NWAVESF];
    __shared__ int s_total;

    const int tid = threadIdx.x, lane = tid & 63, wid = tid >> 6, row = blockIdx.x;
    const float4* xv = (const float4*)(x + (size_t)row * COLS);
    float4* ov = (float4*)(out + (size_t)row * COLS);

    uint32_t pivHi = PIV_HI, loH = 0u, hiH = 0xFFFFFFFFu;
    bool firstPass = true;
    int c = 0;
    for (int attempt = 0; attempt < 64; ++attempt) {
        if (tid == 0) s_cnt = 0;
        __syncthreads();
        #pragma unroll
        for (int j = 0; j < COLS / 4 / TPBF; ++j) {
            const int vi = j * TPBF + tid;
            const float4 v = xv[vi];
            if (firstPass) ov[vi] = make_float4(0.f, 0.f, 0.f, 0.f);
            const uint32_t bidx = (uint32_t)vi * 4u;
            const float vv[4] = {v.x, v.y, v.z, v.w};
            #pragma unroll
            for (int e = 0; e < 4; ++e) {
                const uint32_t k = flip32(vv[e]);
                if (k >= pivHi) {
                    const int pos = atomicAdd(&s_cnt, 1);
                    if (pos < CAPF)
                        cand[pos] = ((unsigned long long)k << 32)
                                  | (unsigned long long)(0xFFFFu - (bidx + e));
                }
            }
        }
        firstPass = false;
        __syncthreads();
        c = s_cnt;
        __syncthreads();
        if (c >= KSEL && c <= CAPF) break;
        if (c > CAPF) { loH = pivHi; pivHi = pivHi + ((hiH - pivHi) >> 1); }
        else          { hiH = pivHi; pivHi = loH + ((pivHi - loH) >> 1); }
    }

    unsigned long long k0 = 0, k1 = 0, k2 = 0, k3 = 0;
    if (tid            < c) k0 = cand[tid];
    if (tid + TPBF     < c) k1 = cand[tid + TPBF];
    if (tid + 2 * TPBF < c) k2 = cand[tid + 2 * TPBF];
    if (tid + 3 * TPBF < c) k3 = cand[tid + 3 * TPBF];

    unsigned long long lo = ((unsigned long long)pivHi << 32) - 1ull, hi = ~0ull, mid = lo;
    int m = c;
    for (int it = 0; it < 72 && m != KSEL; ++it) {
        mid = lo + ((hi - lo) >> 1);
        int local = (int)(k0 > mid) + (int)(k1 > mid) + (int)(k2 > mid) + (int)(k3 > mid);
        #pragma unroll
        for (int off = 32; off >= 1; off >>= 1) local += __shfl_xor(local, off, 64);
        if (lane == 0) s_wsum[wid] = local;
        __syncthreads();
        if (tid == 0) {
            int t = 0;
            #pragma unroll
            for (int w = 0; w < NWAVESF; ++w) t += s_wsum[w];
            s_total = t;
        }
        __syncthreads();
        m = s_total;
        if (m > KSEL) lo = mid; else if (m < KSEL) hi = mid;
    }
    const unsigned long long ks[4] = {k0, k1, k2, k3};
    #pragma unroll
    for (int q = 0; q < 4; ++q) {
        if (ks[q] > mid) {
            const uint32_t idx = 0xFFFFu - (uint32_t)(ks[q] & 0xFFFFull);
            out[(size_t)row * COLS + idx] = fmaxf(unflip32((uint32_t)(ks[q] >> 32)), 0.f);
        }
    }
}

extern "C" void kernel_launch(void* const* d_in, const int* in_sizes, int n_in,
                              void* d_out, int out_size, void* d_ws, size_t ws_size,
                              hipStream_t stream) {
    const float* x = (const float*)d_in[0];
    float* out = (float*)d_out;
    const int rows = in_sizes[0] / COLS;
    const long long n4 = (long long)rows * (COLS / 4);

    const size_t cnt_bytes = (size_t)rows * sizeof(int);
    const size_t cnt_region = (cnt_bytes + 255) & ~(size_t)255;
    long long avail = (long long)ws_size - (long long)cnt_region;
    int cap2 = 0;
    if (avail > 0) {
        long long per = avail / ((long long)rows * 8);
        cap2 = (int)(per > 1024 ? 1024 : per);
    }

    if (cap2 >= 256) {
        int* cnt = (int*)d_ws;
        unsigned long long* slots = (unsigned long long*)((char*)d_ws + cnt_region);
        hipMemsetAsync(cnt, 0, cnt_bytes, stream);
        fill_zero_kernel<<<2048, 256, 0, stream>>>(out, n4);
        collect_kernel<<<2048, 256, 0, stream>>>(x, slots, cnt, cap2, n4);
        select_kernel<<<rows, 64, 0, stream>>>(x, slots, cnt, cap2, out);
    } else {
        topk_fused_kernel<<<rows, TPBF, 0, stream>>>(x, out);
    }
}

// Round 3
// 668.649 us; speedup vs baseline: 1.6594x; 1.0538x over previous
//
#include <hip/hip_runtime.h>
#include <stdint.h>

#define COLS 65536
#define KSEL 32
#define PIV_HI 0xC0300000u   /* flip32(2.75f); rank-32/65536 threshold for N(0,1) ~ 3.30 */

typedef __attribute__((ext_vector_type(4))) float f32x4;

__device__ __forceinline__ uint32_t flip32(float f) {
    uint32_t u = __float_as_uint(f);
    return u ^ ((u & 0x80000000u) ? 0xFFFFFFFFu : 0x80000000u);
}
__device__ __forceinline__ float unflip32(uint32_t k) {
    uint32_t u = k ^ ((k & 0x80000000u) ? 0x80000000u : 0xFFFFFFFFu);
    return __uint_as_float(u);
}

// ---------------- tiny: zero the per-row candidate counters ----------------
__global__ __launch_bounds__(256)
void zero_cnt_kernel(int* __restrict__ cnt, int rows) {
    const int i = blockIdx.x * blockDim.x + threadIdx.x;
    if (i < rows) cnt[i] = 0;
}

// ---------------- Pass 1: streaming candidate filter (pure read stream) ----------------
__global__ __launch_bounds__(256)
void collect_kernel(const float* __restrict__ x, unsigned long long* __restrict__ slots,
                    int* __restrict__ cnt, int cap2, long long n4) {
    const long long stride = (long long)gridDim.x * blockDim.x;
    const float4* xv = (const float4*)x;
    for (long long g = (long long)blockIdx.x * blockDim.x + threadIdx.x; g < n4; g += stride) {
        const float4 v = xv[g];
        const uint32_t f0 = flip32(v.x), f1 = flip32(v.y), f2 = flip32(v.z), f3 = flip32(v.w);
        const int n = (int)(f0 >= PIV_HI) + (int)(f1 >= PIV_HI)
                    + (int)(f2 >= PIV_HI) + (int)(f3 >= PIV_HI);
        if (n) {                                        // ~1.2% of lanes take this
            const int row = (int)(g >> 14);             // 16384 float4 per row
            const uint32_t col0 = ((uint32_t)g & 16383u) << 2;
            int pos = atomicAdd(&cnt[row], n);
            unsigned long long* base = slots + (size_t)row * (size_t)cap2;
            const uint32_t fs[4] = {f0, f1, f2, f3};
            #pragma unroll
            for (int e = 0; e < 4; ++e) {
                if (fs[e] >= PIV_HI) {
                    if (pos < cap2)
                        base[pos] = ((unsigned long long)fs[e] << 32)
                                  | (unsigned long long)(0xFFFFu - (col0 + e));
                    ++pos;
                }
            }
        }
    }
}

// ---- Pass 2: per-row wave bisection (registers+shfl only) + full-row write stream ----
// Block = 256 (4 waves) per row. Each wave redundantly bisects the candidate set (no
// barriers, no LDS), then zero-fills its quarter of the row with NT stores and scatters
// its quarter's winners. Entire output write lives in this one kernel.
__global__ __launch_bounds__(256)
void select_write_kernel(const float* __restrict__ x, const unsigned long long* __restrict__ slots,
                         const int* __restrict__ cnt, int cap2, float* __restrict__ out) {
    const int row  = blockIdx.x;
    const int tid  = threadIdx.x;
    const int lane = tid & 63;
    const int wave = tid >> 6;
    const int c = cnt[row];
    float* __restrict__ orow = out + (size_t)row * COLS;

    unsigned long long k[16];
    unsigned long long mid = 0ull;
    const bool normal = (c >= KSEL && c <= cap2);

    if (normal) {
        const unsigned long long* base = slots + (size_t)row * (size_t)cap2;
        #pragma unroll
        for (int i = 0; i < 16; ++i) {
            const int idx = i * 64 + lane;
            k[i] = (idx < c) ? base[idx] : 0ull;
        }
        // count(key > lo) == c at lo = pivot64; distinct keys => exact-32 window exists.
        unsigned long long lo = ((unsigned long long)PIV_HI << 32) - 1ull;
        unsigned long long hi = ~0ull;
        mid = lo;
        int m = c;
        for (int it = 0; it < 72 && m != KSEL; ++it) {
            mid = lo + ((hi - lo) >> 1);
            int local = 0;
            #pragma unroll
            for (int i = 0; i < 16; ++i) local += (int)(k[i] > mid);
            #pragma unroll
            for (int off = 32; off >= 1; off >>= 1) local += __shfl_xor(local, off, 64);
            m = local;
            if (m > KSEL) lo = mid; else if (m < KSEL) hi = mid;
        }
    } else {
        // Correctness fallback (never taken for N(0,1)): wave-redundant full-row bisection.
        const float* xr = x + (size_t)row * COLS;
        unsigned long long lo = 0ull, hi = ~0ull;
        int m = -1;
        for (int it = 0; it < 96 && m != KSEL; ++it) {
            mid = lo + ((hi - lo) >> 1);
            int local = 0;
            for (int j = lane; j < COLS; j += 64) {
                const unsigned long long key =
                    ((unsigned long long)flip32(xr[j]) << 32)
                    | (unsigned long long)(0xFFFFu - (uint32_t)j);
                local += (int)(key > mid);
            }
            #pragma unroll
            for (int off = 32; off >= 1; off >>= 1) local += __shfl_xor(local, off, 64);
            m = local;
            if (m > KSEL) lo = mid; else if (m < KSEL) hi = mid;
        }
    }

    // Zero-fill my wave's 16K-column segment (pure coalesced NT write stream).
    f32x4* ov = (f32x4*)orow;
    const int segBase4 = wave * 4096;                   // float4 units
    const f32x4 z = (f32x4)(0.f);
    #pragma unroll
    for (int i = 0; i < 64; ++i)
        __builtin_nontemporal_store(z, &ov[segBase4 + i * 64 + lane]);
    // Drain zero stores before scattering winners into the same lines.
    asm volatile("s_waitcnt vmcnt(0)" ::: "memory");

    const uint32_t segLo = (uint32_t)wave * 16384u, segHi = segLo + 16384u;
    if (normal) {
        #pragma unroll
        for (int i = 0; i < 16; ++i) {
            if (k[i] > mid) {
                const uint32_t col = 0xFFFFu - (uint32_t)(k[i] & 0xFFFFull);
                if (col >= segLo && col < segHi)
                    orow[col] = fmaxf(unflip32((uint32_t)(k[i] >> 32)), 0.f);
            }
        }
    } else {
        const float* xr = x + (size_t)row * COLS;
        for (uint32_t j = segLo + lane; j < segHi; j += 64) {
            const float v = xr[j];
            const unsigned long long key =
                ((unsigned long long)flip32(v) << 32)
                | (unsigned long long)(0xFFFFu - j);
            if (key > mid) orow[j] = fmaxf(v, 0.f);
        }
    }
}

// ---------------- Last-resort fused kernel (only if ws_size is tiny) ----------------
#define CAPF 4096
#define TPBF 1024
#define NWAVESF (TPBF / 64)
__global__ __launch_bounds__(TPBF)
void topk_fused_kernel(const float* __restrict__ x, float* __restrict__ out) {
    __shared__ unsigned long long cand[CAPF];
    __shared__ int s_cnt;
    __shared__ int s_wsum[NWAVESF];
    __shared__ int s_total;

    const int tid = threadIdx.x, lane = tid & 63, wid = tid >> 6, row = blockIdx.x;
    const float4* xv = (const float4*)(x + (size_t)row * COLS);
    float4* ov = (float4*)(out + (size_t)row * COLS);

    uint32_t pivHi = PIV_HI, loH = 0u, hiH = 0xFFFFFFFFu;
    bool firstPass = true;
    int c = 0;
    for (int attempt = 0; attempt < 64; ++attempt) {
        if (tid == 0) s_cnt = 0;
        __syncthreads();
        #pragma unroll
        for (int j = 0; j < COLS / 4 / TPBF; ++j) {
            const int vi = j * TPBF + tid;
            const float4 v = xv[vi];
            if (firstPass) ov[vi] = make_float4(0.f, 0.f, 0.f, 0.f);
            const uint32_t bidx = (uint32_t)vi * 4u;
            const float vv[4] = {v.x, v.y, v.z, v.w};
            #pragma unroll
            for (int e = 0; e < 4; ++e) {
                const uint32_t kk = flip32(vv[e]);
                if (kk >= pivHi) {
                    const int pos = atomicAdd(&s_cnt, 1);
                    if (pos < CAPF)
                        cand[pos] = ((unsigned long long)kk << 32)
                                  | (unsigned long long)(0xFFFFu - (bidx + e));
                }
            }
        }
        firstPass = false;
        __syncthreads();
        c = s_cnt;
        __syncthreads();
        if (c >= KSEL && c <= CAPF) break;
        if (c > CAPF) { loH = pivHi; pivHi = pivHi + ((hiH - pivHi) >> 1); }
        else          { hiH = pivHi; pivHi = loH + ((pivHi - loH) >> 1); }
    }

    unsigned long long k0 = 0, k1 = 0, k2 = 0, k3 = 0;
    if (tid            < c) k0 = cand[tid];
    if (tid + TPBF     < c) k1 = cand[tid + TPBF];
    if (tid + 2 * TPBF < c) k2 = cand[tid + 2 * TPBF];
    if (tid + 3 * TPBF < c) k3 = cand[tid + 3 * TPBF];

    unsigned long long lo = ((unsigned long long)pivHi << 32) - 1ull, hi = ~0ull, mid = lo;
    int m = c;
    for (int it = 0; it < 72 && m != KSEL; ++it) {
        mid = lo + ((hi - lo) >> 1);
        int local = (int)(k0 > mid) + (int)(k1 > mid) + (int)(k2 > mid) + (int)(k3 > mid);
        #pragma unroll
        for (int off = 32; off >= 1; off >>= 1) local += __shfl_xor(local, off, 64);
        if (lane == 0) s_wsum[wid] = local;
        __syncthreads();
        if (tid == 0) {
            int t = 0;
            #pragma unroll
            for (int w = 0; w < NWAVESF; ++w) t += s_wsum[w];
            s_total = t;
        }
        __syncthreads();
        m = s_total;
        if (m > KSEL) lo = mid; else if (m < KSEL) hi = mid;
    }
    const unsigned long long ks[4] = {k0, k1, k2, k3};
    #pragma unroll
    for (int q = 0; q < 4; ++q) {
        if (ks[q] > mid) {
            const uint32_t idx = 0xFFFFu - (uint32_t)(ks[q] & 0xFFFFull);
            out[(size_t)row * COLS + idx] = fmaxf(unflip32((uint32_t)(ks[q] >> 32)), 0.f);
        }
    }
}

extern "C" void kernel_launch(void* const* d_in, const int* in_sizes, int n_in,
                              void* d_out, int out_size, void* d_ws, size_t ws_size,
                              hipStream_t stream) {
    const float* x = (const float*)d_in[0];
    float* out = (float*)d_out;
    const int rows = in_sizes[0] / COLS;
    const long long n4 = (long long)rows * (COLS / 4);

    const size_t cnt_bytes = (size_t)rows * sizeof(int);
    const size_t cnt_region = (cnt_bytes + 255) & ~(size_t)255;
    long long avail = (long long)ws_size - (long long)cnt_region;
    int cap2 = 0;
    if (avail > 0) {
        long long per = avail / ((long long)rows * 8);
        cap2 = (int)(per > 1024 ? 1024 : per);
    }

    if (cap2 >= 256) {
        int* cnt = (int*)d_ws;
        unsigned long long* slots = (unsigned long long*)((char*)d_ws + cnt_region);
        zero_cnt_kernel<<<(rows + 255) / 256, 256, 0, stream>>>(cnt, rows);
        collect_kernel<<<2048, 256, 0, stream>>>(x, slots, cnt, cap2, n4);
        select_write_kernel<<<rows, 256, 0, stream>>>(x, slots, cnt, cap2, out);
    } else {
        topk_fused_kernel<<<rows, TPBF, 0, stream>>>(x, out);
    }
}

// Round 4
// 420.939 us; speedup vs baseline: 2.6360x; 1.5885x over previous
//
#include <hip/hip_runtime.h>
#include <stdint.h>

#define COLS 65536
#define KSEL 32
#define PIV_HI 0xC0300000u   /* flip32(2.75f); rank-32/65536 threshold for N(0,1) ~ 3.30 */

typedef __attribute__((ext_vector_type(4))) float f32x4;

__device__ __forceinline__ uint32_t flip32(float f) {
    uint32_t u = __float_as_uint(f);
    return u ^ ((u & 0x80000000u) ? 0xFFFFFFFFu : 0x80000000u);
}
__device__ __forceinline__ float unflip32(uint32_t k) {
    uint32_t u = k ^ ((k & 0x80000000u) ? 0x80000000u : 0xFFFFFFFFu);
    return __uint_as_float(u);
}

// ---------------- Pass 1: block-per-row candidate filter (pure read stream) ----------------
// LDS counter instead of contended global atomics; candidates go straight to this row's
// private slots region; cnt[row] written once at the end (no zero_cnt pass needed).
__global__ __launch_bounds__(256)
void collect_row_kernel(const float* __restrict__ x, unsigned long long* __restrict__ slots,
                        int* __restrict__ cnt, int cap2) {
    __shared__ int s_cnt;
    const int row = blockIdx.x;
    const int tid = threadIdx.x;
    if (tid == 0) s_cnt = 0;
    __syncthreads();

    const float4* xv = (const float4*)(x + (size_t)row * COLS);
    unsigned long long* base = slots + (size_t)row * (size_t)cap2;

    #pragma unroll 4
    for (int j = 0; j < COLS / 4 / 256; ++j) {           // 64 coalesced float4 iters
        const int vi = j * 256 + tid;
        const float4 v = xv[vi];
        const uint32_t f0 = flip32(v.x), f1 = flip32(v.y), f2 = flip32(v.z), f3 = flip32(v.w);
        const int n = (int)(f0 >= PIV_HI) + (int)(f1 >= PIV_HI)
                    + (int)(f2 >= PIV_HI) + (int)(f3 >= PIV_HI);
        if (n) {                                         // ~1.2% of lanes
            int pos = atomicAdd(&s_cnt, n);              // LDS atomic: fast, uncontended
            const uint32_t col0 = (uint32_t)vi << 2;
            const uint32_t fs[4] = {f0, f1, f2, f3};
            #pragma unroll
            for (int e = 0; e < 4; ++e) {
                if (fs[e] >= PIV_HI) {
                    if (pos < cap2)
                        base[pos] = ((unsigned long long)fs[e] << 32)
                                  | (unsigned long long)(0xFFFFu - (col0 + e));
                    ++pos;
                }
            }
        }
    }
    __syncthreads();
    if (tid == 0) cnt[row] = s_cnt;                      // true count (may exceed cap2 -> fallback)
}

// ---- Pass 2: per-row wave bisection (registers+shfl only) + full-row write stream ----
__global__ __launch_bounds__(256)
void select_write_kernel(const float* __restrict__ x, const unsigned long long* __restrict__ slots,
                         const int* __restrict__ cnt, int cap2, float* __restrict__ out) {
    const int row  = blockIdx.x;
    const int tid  = threadIdx.x;
    const int lane = tid & 63;
    const int wave = tid >> 6;
    const int c = cnt[row];
    float* __restrict__ orow = out + (size_t)row * COLS;

    unsigned long long k[16];
    unsigned long long mid = 0ull;
    const bool normal = (c >= KSEL && c <= cap2);

    if (normal) {
        const unsigned long long* base = slots + (size_t)row * (size_t)cap2;
        #pragma unroll
        for (int i = 0; i < 16; ++i) {
            const int idx = i * 64 + lane;
            k[i] = (idx < c) ? base[idx] : 0ull;
        }
        unsigned long long lo = ((unsigned long long)PIV_HI << 32) - 1ull;  // count(>lo) == c
        unsigned long long hi = ~0ull;
        mid = lo;
        int m = c;
        for (int it = 0; it < 72 && m != KSEL; ++it) {
            mid = lo + ((hi - lo) >> 1);
            int local = 0;
            #pragma unroll
            for (int i = 0; i < 16; ++i) local += (int)(k[i] > mid);
            #pragma unroll
            for (int off = 32; off >= 1; off >>= 1) local += __shfl_xor(local, off, 64);
            m = local;
            if (m > KSEL) lo = mid; else if (m < KSEL) hi = mid;
        }
    } else {
        // Correctness fallback (never taken for N(0,1)): wave-redundant full-row bisection.
        const float* xr = x + (size_t)row * COLS;
        unsigned long long lo = 0ull, hi = ~0ull;
        int m = -1;
        for (int it = 0; it < 96 && m != KSEL; ++it) {
            mid = lo + ((hi - lo) >> 1);
            int local = 0;
            for (int j = lane; j < COLS; j += 64) {
                const unsigned long long key =
                    ((unsigned long long)flip32(xr[j]) << 32)
                    | (unsigned long long)(0xFFFFu - (uint32_t)j);
                local += (int)(key > mid);
            }
            #pragma unroll
            for (int off = 32; off >= 1; off >>= 1) local += __shfl_xor(local, off, 64);
            m = local;
            if (m > KSEL) lo = mid; else if (m < KSEL) hi = mid;
        }
    }

    // Zero-fill my wave's quarter of the row (pure coalesced NT write stream).
    f32x4* ov = (f32x4*)orow;
    const int segBase4 = wave * 4096;                    // float4 units
    const f32x4 z = (f32x4)(0.f);
    #pragma unroll
    for (int i = 0; i < 64; ++i)
        __builtin_nontemporal_store(z, &ov[segBase4 + i * 64 + lane]);
    asm volatile("s_waitcnt vmcnt(0)" ::: "memory");     // drain zeros before scatter

    const uint32_t segLo = (uint32_t)wave * 16384u, segHi = segLo + 16384u;
    if (normal) {
        #pragma unroll
        for (int i = 0; i < 16; ++i) {
            if (k[i] > mid) {
                const uint32_t col = 0xFFFFu - (uint32_t)(k[i] & 0xFFFFull);
                if (col >= segLo && col < segHi)
                    orow[col] = fmaxf(unflip32((uint32_t)(k[i] >> 32)), 0.f);
            }
        }
    } else {
        const float* xr = x + (size_t)row * COLS;
        for (uint32_t j = segLo + lane; j < segHi; j += 64) {
            const float v = xr[j];
            const unsigned long long key =
                ((unsigned long long)flip32(v) << 32)
                | (unsigned long long)(0xFFFFu - j);
            if (key > mid) orow[j] = fmaxf(v, 0.f);
        }
    }
}

// ---------------- Last-resort fused kernel (only if ws_size is tiny) ----------------
#define CAPF 4096
#define TPBF 1024
#define NWAVESF (TPBF / 64)
__global__ __launch_bounds__(TPBF)
void topk_fused_kernel(const float* __restrict__ x, float* __restrict__ out) {
    __shared__ unsigned long long cand[CAPF];
    __shared__ int s_cnt;
    __shared__ int s_wsum[NWAVESF];
    __shared__ int s_total;

    const int tid = threadIdx.x, lane = tid & 63, wid = tid >> 6, row = blockIdx.x;
    const float4* xv = (const float4*)(x + (size_t)row * COLS);
    float4* ov = (float4*)(out + (size_t)row * COLS);

    uint32_t pivHi = PIV_HI, loH = 0u, hiH = 0xFFFFFFFFu;
    bool firstPass = true;
    int c = 0;
    for (int attempt = 0; attempt < 64; ++attempt) {
        if (tid == 0) s_cnt = 0;
        __syncthreads();
        #pragma unroll
        for (int j = 0; j < COLS / 4 / TPBF; ++j) {
            const int vi = j * TPBF + tid;
            const float4 v = xv[vi];
            if (firstPass) ov[vi] = make_float4(0.f, 0.f, 0.f, 0.f);
            const uint32_t bidx = (uint32_t)vi * 4u;
            const float vv[4] = {v.x, v.y, v.z, v.w};
            #pragma unroll
            for (int e = 0; e < 4; ++e) {
                const uint32_t kk = flip32(vv[e]);
                if (kk >= pivHi) {
                    const int pos = atomicAdd(&s_cnt, 1);
                    if (pos < CAPF)
                        cand[pos] = ((unsigned long long)kk << 32)
                                  | (unsigned long long)(0xFFFFu - (bidx + e));
                }
            }
        }
        firstPass = false;
        __syncthreads();
        c = s_cnt;
        __syncthreads();
        if (c >= KSEL && c <= CAPF) break;
        if (c > CAPF) { loH = pivHi; pivHi = pivHi + ((hiH - pivHi) >> 1); }
        else          { hiH = pivHi; pivHi = loH + ((pivHi - loH) >> 1); }
    }

    unsigned long long k0 = 0, k1 = 0, k2 = 0, k3 = 0;
    if (tid            < c) k0 = cand[tid];
    if (tid + TPBF     < c) k1 = cand[tid + TPBF];
    if (tid + 2 * TPBF < c) k2 = cand[tid + 2 * TPBF];
    if (tid + 3 * TPBF < c) k3 = cand[tid + 3 * TPBF];

    unsigned long long lo = ((unsigned long long)pivHi << 32) - 1ull, hi = ~0ull, mid = lo;
    int m = c;
    for (int it = 0; it < 72 && m != KSEL; ++it) {
        mid = lo + ((hi - lo) >> 1);
        int local = (int)(k0 > mid) + (int)(k1 > mid) + (int)(k2 > mid) + (int)(k3 > mid);
        #pragma unroll
        for (int off = 32; off >= 1; off >>= 1) local += __shfl_xor(local, off, 64);
        if (lane == 0) s_wsum[wid] = local;
        __syncthreads();
        if (tid == 0) {
            int t = 0;
            #pragma unroll
            for (int w = 0; w < NWAVESF; ++w) t += s_wsum[w];
            s_total = t;
        }
        __syncthreads();
        m = s_total;
        if (m > KSEL) lo = mid; else if (m < KSEL) hi = mid;
    }
    const unsigned long long ks[4] = {k0, k1, k2, k3};
    #pragma unroll
    for (int q = 0; q < 4; ++q) {
        if (ks[q] > mid) {
            const uint32_t idx = 0xFFFFu - (uint32_t)(ks[q] & 0xFFFFull);
            out[(size_t)row * COLS + idx] = fmaxf(unflip32((uint32_t)(ks[q] >> 32)), 0.f);
        }
    }
}

extern "C" void kernel_launch(void* const* d_in, const int* in_sizes, int n_in,
                              void* d_out, int out_size, void* d_ws, size_t ws_size,
                              hipStream_t stream) {
    const float* x = (const float*)d_in[0];
    float* out = (float*)d_out;
    const int rows = in_sizes[0] / COLS;

    const size_t cnt_bytes = (size_t)rows * sizeof(int);
    const size_t cnt_region = (cnt_bytes + 255) & ~(size_t)255;
    long long avail = (long long)ws_size - (long long)cnt_region;
    int cap2 = 0;
    if (avail > 0) {
        long long per = avail / ((long long)rows * 8);
        cap2 = (int)(per > 1024 ? 1024 : per);
    }

    if (cap2 >= 256) {
        int* cnt = (int*)d_ws;
        unsigned long long* slots = (unsigned long long*)((char*)d_ws + cnt_region);
        collect_row_kernel<<<rows, 256, 0, stream>>>(x, slots, cnt, cap2);
        select_write_kernel<<<rows, 256, 0, stream>>>(x, slots, cnt, cap2, out);
    } else {
        topk_fused_kernel<<<rows, TPBF, 0, stream>>>(x, out);
    }
}

// Round 5
// 391.833 us; speedup vs baseline: 2.8318x; 1.0743x over previous
//
#include <hip/hip_runtime.h>
#include <stdint.h>

#define COLS 65536
#define KSEL 32
#define TPB 256
#define CAP 1024
#define PIV_HI 0xC0300000u   /* flip32(2.75f); rank-32/65536 threshold for N(0,1) ~ 3.30 */

typedef __attribute__((ext_vector_type(4))) float f32x4;

__device__ __forceinline__ uint32_t flip32(float f) {
    uint32_t u = __float_as_uint(f);
    return u ^ ((u & 0x80000000u) ? 0xFFFFFFFFu : 0x80000000u);
}
__device__ __forceinline__ float unflip32(uint32_t k) {
    uint32_t u = k ^ ((k & 0x80000000u) ? 0x80000000u : 0xFFFFFFFFu);
    return __uint_as_float(u);
}

// One block per row. Phase-separated copy-shaped kernel:
//   (1) stream-read row, filter candidates into LDS (expected ~195 of 65536)
//   (2) NT zero-fill this wave's quarter of the output row (independent of selection)
//   (3) per-wave register bisection over candidate keys (shfl-only) while zeros drain
//   (4) vmcnt(0), scatter the 32 winners
// Key = (flip32(value) << 32) | (0xFFFF - col): strictly monotone in (value desc, col asc),
// all keys distinct => exact rank-32 boundary exists; matches jax.lax.top_k tie order.
__global__ __launch_bounds__(TPB)
void topk_onepass_kernel(const float* __restrict__ x, float* __restrict__ out) {
    __shared__ unsigned long long cand[CAP];   // 8 KiB
    __shared__ int s_cnt;

    const int row  = blockIdx.x;
    const int tid  = threadIdx.x;
    const int lane = tid & 63;
    const int wave = tid >> 6;

    if (tid == 0) s_cnt = 0;
    __syncthreads();

    const f32x4* __restrict__ xv = (const f32x4*)(x + (size_t)row * COLS);
    float* __restrict__ orow = out + (size_t)row * COLS;
    f32x4* __restrict__ ov = (f32x4*)orow;

    // ---- Phase 1: pure read stream + rare candidate capture into LDS.
    #pragma unroll 8
    for (int j = 0; j < COLS / 4 / TPB; ++j) {           // 64 coalesced float4 iters
        const int vi = j * TPB + tid;
        const f32x4 v = __builtin_nontemporal_load(&xv[vi]);
        const uint32_t f0 = flip32(v.x), f1 = flip32(v.y), f2 = flip32(v.z), f3 = flip32(v.w);
        const int n = (int)(f0 >= PIV_HI) + (int)(f1 >= PIV_HI)
                    + (int)(f2 >= PIV_HI) + (int)(f3 >= PIV_HI);
        if (n) {                                         // ~1.2% of lane-iterations
            int pos = atomicAdd(&s_cnt, n);              // LDS atomic, uncontended
            const uint32_t col0 = (uint32_t)vi << 2;
            const uint32_t fs[4] = {f0, f1, f2, f3};
            #pragma unroll
            for (int e = 0; e < 4; ++e) {
                if (fs[e] >= PIV_HI) {
                    if (pos < CAP)
                        cand[pos] = ((unsigned long long)fs[e] << 32)
                                  | (unsigned long long)(0xFFFFu - (col0 + e));
                    ++pos;
                }
            }
        }
    }
    __syncthreads();
    const int c = s_cnt;

    const int segBase4 = wave * 4096;                    // this wave's quarter (float4 units)
    const uint32_t segLo = (uint32_t)wave * 16384u, segHi = segLo + 16384u;
    const f32x4 z = (f32x4)(0.f);

    if (c >= KSEL && c <= CAP) {
        // ---- Phase 2: issue the quarter-row NT zero-fill (no dependency on selection).
        #pragma unroll
        for (int i = 0; i < 64; ++i)
            __builtin_nontemporal_store(z, &ov[segBase4 + i * 64 + lane]);

        // ---- Phase 3: per-wave redundant bisection over LDS candidates (overlaps drain).
        unsigned long long k[16];
        #pragma unroll
        for (int i = 0; i < 16; ++i) {
            const int idx = i * 64 + lane;
            k[i] = (idx < c) ? cand[idx] : 0ull;
        }
        unsigned long long lo = ((unsigned long long)PIV_HI << 32) - 1ull;  // count(>lo)==c
        unsigned long long hi = ~0ull;
        unsigned long long mid = lo;
        int m = c;
        for (int it = 0; it < 72 && m != KSEL; ++it) {
            mid = lo + ((hi - lo) >> 1);
            int local = 0;
            #pragma unroll
            for (int i = 0; i < 16; ++i) local += (int)(k[i] > mid);
            #pragma unroll
            for (int off = 32; off >= 1; off >>= 1) local += __shfl_xor(local, off, 64);
            m = local;
            if (m > KSEL) lo = mid; else if (m < KSEL) hi = mid;
        }

        // ---- Phase 4: drain zeros, scatter winners in my quarter.
        asm volatile("s_waitcnt vmcnt(0)" ::: "memory");
        #pragma unroll
        for (int i = 0; i < 16; ++i) {
            if (k[i] > mid) {
                const uint32_t col = 0xFFFFu - (uint32_t)(k[i] & 0xFFFFull);
                if (col >= segLo && col < segHi)
                    orow[col] = fmaxf(unflip32((uint32_t)(k[i] >> 32)), 0.f);
            }
        }
    } else {
        // Correctness fallback (P ~ 0 for N(0,1) data): wave-redundant full-row bisection
        // straight from global, then fill + scatter by re-reading my quarter.
        const float* __restrict__ xr = x + (size_t)row * COLS;
        unsigned long long lo = 0ull, hi = ~0ull, mid = 0ull;
        int m = -1;
        for (int it = 0; it < 96 && m != KSEL; ++it) {
            mid = lo + ((hi - lo) >> 1);
            int local = 0;
            for (int j = lane; j < COLS; j += 64) {
                const unsigned long long key =
                    ((unsigned long long)flip32(xr[j]) << 32)
                    | (unsigned long long)(0xFFFFu - (uint32_t)j);
                local += (int)(key > mid);
            }
            #pragma unroll
            for (int off = 32; off >= 1; off >>= 1) local += __shfl_xor(local, off, 64);
            m = local;
            if (m > KSEL) lo = mid; else if (m < KSEL) hi = mid;
        }
        #pragma unroll
        for (int i = 0; i < 64; ++i)
            __builtin_nontemporal_store(z, &ov[segBase4 + i * 64 + lane]);
        asm volatile("s_waitcnt vmcnt(0)" ::: "memory");
        for (uint32_t j = segLo + lane; j < segHi; j += 64) {
            const float v = xr[j];
            const unsigned long long key =
                ((unsigned long long)flip32(v) << 32)
                | (unsigned long long)(0xFFFFu - j);
            if (key > mid) orow[j] = fmaxf(v, 0.f);
        }
    }
}

extern "C" void kernel_launch(void* const* d_in, const int* in_sizes, int n_in,
                              void* d_out, int out_size, void* d_ws, size_t ws_size,
                              hipStream_t stream) {
    const float* x = (const float*)d_in[0];
    float* out = (float*)d_out;
    const int rows = in_sizes[0] / COLS;
    topk_onepass_kernel<<<rows, TPB, 0, stream>>>(x, out);
}